// Round 2
// baseline (481.117 us; speedup 1.0000x reference)
//
#include <hip/hip_runtime.h>

typedef __attribute__((ext_vector_type(8))) short short8;
typedef __attribute__((ext_vector_type(4))) float f32x4;

#define AS1 __attribute__((address_space(1)))
#define AS3 __attribute__((address_space(3)))

__device__ __forceinline__ void gload_lds16(const void* g, void* l) {
  __builtin_amdgcn_global_load_lds((const AS1 void*)g, (AS3 void*)l, 16, 0, 0);
}

__device__ __forceinline__ unsigned short f2bf(float f) {
  unsigned int u = __float_as_uint(f);
  u += 0x7fffu + ((u >> 16) & 1u);
  return (unsigned short)(u >> 16);
}

// ---------------- x: fp32 -> bf16, 8 elems/thread ----------------
__global__ __launch_bounds__(256) void k_convert(const float* __restrict__ in,
                                                 unsigned short* __restrict__ out) {
  long i = (long)blockIdx.x * 256 + threadIdx.x;
  const float4* p = (const float4*)in + i * 2;
  float4 a = p[0], b = p[1];
  short8 o;
  o[0] = (short)f2bf(a.x); o[1] = (short)f2bf(a.y);
  o[2] = (short)f2bf(a.z); o[3] = (short)f2bf(a.w);
  o[4] = (short)f2bf(b.x); o[5] = (short)f2bf(b.y);
  o[6] = (short)f2bf(b.z); o[7] = (short)f2bf(b.w);
  ((short8*)out)[i] = o;
}

// ---------- W [K][N] fp32 -> WT [N][K] bf16 (64x64 tiles) ----------
__global__ __launch_bounds__(256) void k_transpose_w(const float* __restrict__ w,
                                                     unsigned short* __restrict__ wt,
                                                     int K, int N) {
  __shared__ float t[64][65];
  const int tilesN = N >> 6;
  const int tk = blockIdx.x / tilesN, tn = blockIdx.x % tilesN;
  const int c = threadIdx.x & 63, r0 = (threadIdx.x >> 6) * 16;
#pragma unroll
  for (int i = 0; i < 16; ++i)
    t[r0 + i][c] = w[(long)(tk * 64 + r0 + i) * N + tn * 64 + c];
  __syncthreads();
#pragma unroll
  for (int i = 0; i < 16; ++i)
    wt[(long)(tn * 64 + r0 + i) * K + tk * 64 + c] = f2bf(t[c][r0 + i]);
}

// ---------- V part of qkv -> VT [bh*64 + d][2048] bf16 ----------
__global__ __launch_bounds__(256) void k_transpose_v(const unsigned short* __restrict__ qkv,
                                                     unsigned short* __restrict__ vt) {
  __shared__ __align__(16) unsigned short t[64][72];
  const int tt = blockIdx.x & 31, bh = blockIdx.x >> 5;
  const int b = bh >> 4, h = bh & 15;
  const int r = threadIdx.x >> 2, c0 = (threadIdx.x & 3) * 16;
  const unsigned short* src = qkv + (long)(b * 2048 + tt * 64 + r) * 3072 + 2048 + h * 64 + c0;
  *(short8*)&t[r][c0] = *(const short8*)src;
  *(short8*)&t[r][c0 + 8] = *(const short8*)(src + 8);
  __syncthreads();
  short8 w0, w1;
#pragma unroll
  for (int i = 0; i < 8; ++i) w0[i] = (short)t[c0 + i][r];
#pragma unroll
  for (int i = 0; i < 8; ++i) w1[i] = (short)t[c0 + 8 + i][r];
  unsigned short* dst = vt + (long)(bh * 64 + r) * 2048 + tt * 64 + c0;
  *(short8*)dst = w0;
  *(short8*)(dst + 8) = w1;
}

// ---------- GEMM: C[M][N] = A[M][K] @ BT[N][K]^T + bias, 128x128 tile ----------
template <int OUT_BF16>
__global__ __launch_bounds__(256) void k_gemm(const unsigned short* __restrict__ A,
                                              const unsigned short* __restrict__ BT,
                                              const float* __restrict__ bias,
                                              void* __restrict__ out,
                                              int M, int N, int K) {
  __shared__ __align__(16) unsigned short As[128 * 64];
  __shared__ __align__(16) unsigned short Bs[128 * 64];
  const int tid = threadIdx.x, lane = tid & 63, wid = tid >> 6;
  const int r16 = lane & 15, khi = lane >> 4;
  const int wr = wid >> 1, wc = wid & 1;
  const int tilesN = N >> 7;
  const int tm = blockIdx.x / tilesN, tn = blockIdx.x % tilesN;
  const long m0 = (long)tm * 128, n0 = (long)tn * 128;
  f32x4 acc[4][4] = {};
  const int srow = tid >> 3, scol = (tid & 7) * 8;  // staging: 8 threads per 64-elem row

  for (int k0 = 0; k0 < K; k0 += 64) {
#pragma unroll
    for (int call = 0; call < 4; ++call) {
      int row = call * 32 + srow;
      gload_lds16(A + (m0 + row) * K + k0 + scol, &As[call * 2048 + wid * 512]);
      gload_lds16(BT + (n0 + row) * K + k0 + scol, &Bs[call * 2048 + wid * 512]);
    }
    __syncthreads();  // drains vmcnt(0) -> staged data visible
#pragma unroll
    for (int kk = 0; kk < 2; ++kk) {
      short8 af[4], bf[4];
#pragma unroll
      for (int m = 0; m < 4; ++m)
        af[m] = *(const short8*)&As[(wr * 64 + m * 16 + r16) * 64 + kk * 32 + khi * 8];
#pragma unroll
      for (int n = 0; n < 4; ++n)
        bf[n] = *(const short8*)&Bs[(wc * 64 + n * 16 + r16) * 64 + kk * 32 + khi * 8];
#pragma unroll
      for (int m = 0; m < 4; ++m)
#pragma unroll
        for (int n = 0; n < 4; ++n)
          acc[m][n] = __builtin_amdgcn_mfma_f32_16x16x32_bf16(af[m], bf[n], acc[m][n], 0, 0, 0);
    }
    __syncthreads();
  }
  // epilogue: C layout col=lane&15, row=(lane>>4)*4+reg
#pragma unroll
  for (int m = 0; m < 4; ++m) {
    long row = m0 + wr * 64 + m * 16 + khi * 4;
#pragma unroll
    for (int n = 0; n < 4; ++n) {
      int col = (int)n0 + wc * 64 + n * 16 + r16;
      float bv = bias[col];
#pragma unroll
      for (int j = 0; j < 4; ++j) {
        float v = acc[m][n][j] + bv;
        if (OUT_BF16)
          ((unsigned short*)out)[(row + j) * N + col] = f2bf(v);
        else
          ((float*)out)[(row + j) * N + col] = v;
      }
    }
  }
}

// ---------- causal flash attention, QBLK=64, KVBLK=64, HDIM=64 ----------
// grid.x = 32 qtiles * 64 bh; 4 waves, wave w owns S rows w*16..w*16+16
__global__ __launch_bounds__(256) void k_attn(const unsigned short* __restrict__ qkv,
                                              const unsigned short* __restrict__ vt,
                                              unsigned short* __restrict__ aout) {
  __shared__ __align__(16) unsigned short Qs[64 * 64];
  __shared__ __align__(16) unsigned short Ks[64 * 64];
  __shared__ __align__(16) unsigned short VTs[64 * 64];
  __shared__ __align__(16) unsigned short Ps[64 * 72];
  const int tid = threadIdx.x, lane = tid & 63, wid = tid >> 6;
  const int r16 = lane & 15, khi = lane >> 4;
  const int qt = blockIdx.x & 31, bh = blockIdx.x >> 5;
  const int b = bh >> 4, h = bh & 15;
  const long qrow0 = (long)b * 2048 + qt * 64;
  const int srow = tid >> 3, scol = (tid & 7) * 8;  // 64x64 tile staging

  // stage Q once
#pragma unroll
  for (int call = 0; call < 2; ++call) {
    int row = call * 32 + srow;
    gload_lds16(qkv + (qrow0 + row) * 3072 + h * 64 + scol, &Qs[call * 2048 + wid * 512]);
  }
  __syncthreads();
  short8 aq[2];
  aq[0] = *(const short8*)&Qs[(wid * 16 + r16) * 64 + khi * 8];
  aq[1] = *(const short8*)&Qs[(wid * 16 + r16) * 64 + 32 + khi * 8];

  float m_run[4], l_run[4];
  f32x4 o[4] = {};
#pragma unroll
  for (int j = 0; j < 4; ++j) { m_run[j] = -1e30f; l_run[j] = 0.f; }

  for (int kt = 0; kt <= qt; ++kt) {
#pragma unroll
    for (int call = 0; call < 2; ++call) {
      int row = call * 32 + srow;
      gload_lds16(qkv + ((long)b * 2048 + kt * 64 + row) * 3072 + 1024 + h * 64 + scol,
                  &Ks[call * 2048 + wid * 512]);
      gload_lds16(vt + ((long)bh * 64 + row) * 2048 + kt * 64 + scol,
                  &VTs[call * 2048 + wid * 512]);
    }
    __syncthreads();

    // S = Q @ K^T  (K tile is natively the BT operand)
    f32x4 s[4] = {};
#pragma unroll
    for (int kk = 0; kk < 2; ++kk)
#pragma unroll
      for (int n = 0; n < 4; ++n) {
        short8 kb = *(const short8*)&Ks[(n * 16 + r16) * 64 + kk * 32 + khi * 8];
        s[n] = __builtin_amdgcn_mfma_f32_16x16x32_bf16(aq[kk], kb, s[n], 0, 0, 0);
      }
    // scale + causal mask (only on diagonal tile)
    const bool diag = (kt == qt);
#pragma unroll
    for (int n = 0; n < 4; ++n)
#pragma unroll
      for (int j = 0; j < 4; ++j) {
        float v = s[n][j] * 0.125f;
        if (diag) {
          int qrow = wid * 16 + khi * 4 + j;
          int kcol = n * 16 + r16;
          if (kcol > qrow) v = -1e30f;
        }
        s[n][j] = v;
      }
    // row max across 64 cols: per-lane over n, then 16-lane butterfly
    float pm[4];
#pragma unroll
    for (int j = 0; j < 4; ++j)
      pm[j] = fmaxf(fmaxf(s[0][j], s[1][j]), fmaxf(s[2][j], s[3][j]));
#pragma unroll
    for (int x = 1; x < 16; x <<= 1)
#pragma unroll
      for (int j = 0; j < 4; ++j) pm[j] = fmaxf(pm[j], __shfl_xor(pm[j], x, 64));
    float alpha[4], rs[4];
#pragma unroll
    for (int j = 0; j < 4; ++j) {
      float mn = fmaxf(m_run[j], pm[j]);
      alpha[j] = __expf(m_run[j] - mn);
      m_run[j] = mn;
    }
#pragma unroll
    for (int n = 0; n < 4; ++n)
#pragma unroll
      for (int j = 0; j < 4; ++j) s[n][j] = __expf(s[n][j] - m_run[j]);
#pragma unroll
    for (int j = 0; j < 4; ++j) rs[j] = s[0][j] + s[1][j] + s[2][j] + s[3][j];
#pragma unroll
    for (int x = 1; x < 16; x <<= 1)
#pragma unroll
      for (int j = 0; j < 4; ++j) rs[j] += __shfl_xor(rs[j], x, 64);
#pragma unroll
    for (int j = 0; j < 4; ++j) l_run[j] = l_run[j] * alpha[j] + rs[j];
#pragma unroll
    for (int n = 0; n < 4; ++n)
#pragma unroll
      for (int j = 0; j < 4; ++j) o[n][j] *= alpha[j];
    // P -> LDS bf16 (wave-local rows; DS pipe in-order per wave, no barrier)
#pragma unroll
    for (int n = 0; n < 4; ++n)
#pragma unroll
      for (int j = 0; j < 4; ++j)
        Ps[(wid * 16 + khi * 4 + j) * 72 + n * 16 + r16] = f2bf(s[n][j]);
    // O += P @ V  (VT tile is the BT operand)
#pragma unroll
    for (int kk = 0; kk < 2; ++kk) {
      short8 pa = *(const short8*)&Ps[(wid * 16 + r16) * 72 + kk * 32 + khi * 8];
#pragma unroll
      for (int n = 0; n < 4; ++n) {
        short8 vb = *(const short8*)&VTs[(n * 16 + r16) * 64 + kk * 32 + khi * 8];
        o[n] = __builtin_amdgcn_mfma_f32_16x16x32_bf16(pa, vb, o[n], 0, 0, 0);
      }
    }
    __syncthreads();  // protect Ks/VTs before next stage
  }
  // epilogue: write [B,T,H*64] bf16
#pragma unroll
  for (int n = 0; n < 4; ++n) {
    int col = h * 64 + n * 16 + r16;
#pragma unroll
    for (int j = 0; j < 4; ++j) {
      long row = qrow0 + wid * 16 + khi * 4 + j;
      aout[row * 1024 + col] = f2bf(o[n][j] / l_run[j]);
    }
  }
}

extern "C" void kernel_launch(void* const* d_in, const int* in_sizes, int n_in,
                              void* d_out, int out_size, void* d_ws, size_t ws_size,
                              hipStream_t stream) {
  (void)in_sizes; (void)n_in; (void)out_size; (void)ws_size;
  const float* x = (const float*)d_in[0];
  const float* Wqkv = (const float*)d_in[1];
  const float* bqkv = (const float*)d_in[2];
  const float* Wout = (const float*)d_in[3];
  const float* bout = (const float*)d_in[4];
  char* ws = (char*)d_ws;
  // Buffer plan (peak 88 MB):
  //   xb    [8192][1024] bf16 @ 0        (16 MB)  -- dead after GEMM1; aout aliases it
  //   wqkvt [3072][1024] bf16 @ 16 MB    ( 6 MB)
  //   woutt [1024][1024] bf16 @ 22 MB    ( 2 MB)
  //   qkv   [8192][3072] bf16 @ 24 MB    (48 MB)
  //   vt    [4096][2048] bf16 @ 72 MB    (16 MB)
  unsigned short* xb    = (unsigned short*)(ws + 0);
  unsigned short* wqkvt = (unsigned short*)(ws + (16l << 20));
  unsigned short* woutt = (unsigned short*)(ws + (22l << 20));
  unsigned short* qkv   = (unsigned short*)(ws + (24l << 20));
  unsigned short* vt    = (unsigned short*)(ws + (72l << 20));
  unsigned short* aout  = xb;  // alias: xb dead after GEMM1

  k_convert<<<4096, 256, 0, stream>>>(x, xb);
  k_transpose_w<<<768, 256, 0, stream>>>(Wqkv, wqkvt, 1024, 3072);
  k_transpose_w<<<256, 256, 0, stream>>>(Wout, woutt, 1024, 1024);
  k_gemm<1><<<64 * 24, 256, 0, stream>>>(xb, wqkvt, bqkv, qkv, 8192, 3072, 1024);
  k_transpose_v<<<2048, 256, 0, stream>>>(qkv, vt);
  k_attn<<<32 * 64, 256, 0, stream>>>(qkv, vt, aout);
  k_gemm<0><<<64 * 8, 256, 0, stream>>>(aout, woutt, bout, d_out, 8192, 1024, 1024);
}

// Round 5
// 286.077 us; speedup vs baseline: 1.6818x; 1.6818x over previous
//
#include <hip/hip_runtime.h>

typedef __attribute__((ext_vector_type(8))) short short8;
typedef __attribute__((ext_vector_type(4))) short s16x4;
typedef __attribute__((ext_vector_type(4))) float f32x4;

#define AS1 __attribute__((address_space(1)))
#define AS3 __attribute__((address_space(3)))

__device__ __forceinline__ void gload_lds16(const void* g, void* l) {
  __builtin_amdgcn_global_load_lds((const AS1 void*)g, (AS3 void*)l, 16, 0, 0);
}

__device__ __forceinline__ unsigned short f2bf(float f) {
  unsigned int u = __float_as_uint(f);
  u += 0x7fffu + ((u >> 16) & 1u);
  return (unsigned short)(u >> 16);
}

// ---------------- x: fp32 -> bf16, 8 elems/thread ----------------
__global__ __launch_bounds__(256) void k_convert(const float* __restrict__ in,
                                                 unsigned short* __restrict__ out) {
  long i = (long)blockIdx.x * 256 + threadIdx.x;
  const float4* p = (const float4*)in + i * 2;
  float4 a = p[0], b = p[1];
  short8 o;
  o[0] = (short)f2bf(a.x); o[1] = (short)f2bf(a.y);
  o[2] = (short)f2bf(a.z); o[3] = (short)f2bf(a.w);
  o[4] = (short)f2bf(b.x); o[5] = (short)f2bf(b.y);
  o[6] = (short)f2bf(b.z); o[7] = (short)f2bf(b.w);
  ((short8*)out)[i] = o;
}

// ---------- W [K][N] fp32 -> WT [N][K] bf16 (64x64 tiles) ----------
__global__ __launch_bounds__(256) void k_transpose_w(const float* __restrict__ w,
                                                     unsigned short* __restrict__ wt,
                                                     int K, int N) {
  __shared__ float t[64][65];
  const int tilesN = N >> 6;
  const int tk = blockIdx.x / tilesN, tn = blockIdx.x % tilesN;
  const int c = threadIdx.x & 63, r0 = (threadIdx.x >> 6) * 16;
#pragma unroll
  for (int i = 0; i < 16; ++i)
    t[r0 + i][c] = w[(long)(tk * 64 + r0 + i) * N + tn * 64 + c];
  __syncthreads();
#pragma unroll
  for (int i = 0; i < 16; ++i)
    wt[(long)(tn * 64 + r0 + i) * K + tk * 64 + c] = f2bf(t[c][r0 + i]);
}

// ---------- V part of qkv -> VT [bh*64 + d][2048] bf16 ----------
__global__ __launch_bounds__(256) void k_transpose_v(const unsigned short* __restrict__ qkv,
                                                     unsigned short* __restrict__ vt) {
  __shared__ __align__(16) unsigned short t[64][72];
  const int tt = blockIdx.x & 31, bh = blockIdx.x >> 5;
  const int b = bh >> 4, h = bh & 15;
  const int r = threadIdx.x >> 2, c0 = (threadIdx.x & 3) * 16;
  const unsigned short* src = qkv + (long)(b * 2048 + tt * 64 + r) * 3072 + 2048 + h * 64 + c0;
  *(short8*)&t[r][c0] = *(const short8*)src;
  *(short8*)&t[r][c0 + 8] = *(const short8*)(src + 8);
  __syncthreads();
  short8 w0, w1;
#pragma unroll
  for (int i = 0; i < 8; ++i) w0[i] = (short)t[c0 + i][r];
#pragma unroll
  for (int i = 0; i < 8; ++i) w1[i] = (short)t[c0 + 8 + i][r];
  unsigned short* dst = vt + (long)(bh * 64 + r) * 2048 + tt * 64 + c0;
  *(short8*)dst = w0;
  *(short8*)(dst + 8) = w1;
}

// ---------- GEMM: C[M][N] = A[M][K] @ BT[N][K]^T + bias, 128x128 tile ----------
template <int OUT_BF16>
__global__ __launch_bounds__(256) void k_gemm(const unsigned short* __restrict__ A,
                                              const unsigned short* __restrict__ BT,
                                              const float* __restrict__ bias,
                                              void* __restrict__ out,
                                              int M, int N, int K) {
  __shared__ __align__(16) unsigned short As[128 * 64];
  __shared__ __align__(16) unsigned short Bs[128 * 64];
  const int tid = threadIdx.x, lane = tid & 63, wid = tid >> 6;
  const int r16 = lane & 15, khi = lane >> 4;
  const int wr = wid >> 1, wc = wid & 1;
  const int tilesN = N >> 7;
  const int tm = blockIdx.x / tilesN, tn = blockIdx.x % tilesN;
  const long m0 = (long)tm * 128, n0 = (long)tn * 128;
  f32x4 acc[4][4] = {};
  const int srow = tid >> 3, scol = (tid & 7) * 8;  // staging: 8 threads per 64-elem row

  for (int k0 = 0; k0 < K; k0 += 64) {
#pragma unroll
    for (int call = 0; call < 4; ++call) {
      int row = call * 32 + srow;
      gload_lds16(A + (m0 + row) * K + k0 + scol, &As[call * 2048 + wid * 512]);
      gload_lds16(BT + (n0 + row) * K + k0 + scol, &Bs[call * 2048 + wid * 512]);
    }
    __syncthreads();  // drains vmcnt(0) -> staged data visible
#pragma unroll
    for (int kk = 0; kk < 2; ++kk) {
      short8 af[4], bf[4];
#pragma unroll
      for (int m = 0; m < 4; ++m)
        af[m] = *(const short8*)&As[(wr * 64 + m * 16 + r16) * 64 + kk * 32 + khi * 8];
#pragma unroll
      for (int n = 0; n < 4; ++n)
        bf[n] = *(const short8*)&Bs[(wc * 64 + n * 16 + r16) * 64 + kk * 32 + khi * 8];
#pragma unroll
      for (int m = 0; m < 4; ++m)
#pragma unroll
        for (int n = 0; n < 4; ++n)
          acc[m][n] = __builtin_amdgcn_mfma_f32_16x16x32_bf16(af[m], bf[n], acc[m][n], 0, 0, 0);
    }
    __syncthreads();
  }
  // epilogue: C layout col=lane&15, row=(lane>>4)*4+reg
#pragma unroll
  for (int m = 0; m < 4; ++m) {
    long row = m0 + wr * 64 + m * 16 + khi * 4;
#pragma unroll
    for (int n = 0; n < 4; ++n) {
      int col = (int)n0 + wc * 64 + n * 16 + r16;
      float bv = bias[col];
#pragma unroll
      for (int j = 0; j < 4; ++j) {
        float v = acc[m][n][j] + bv;
        if (OUT_BF16)
          ((unsigned short*)out)[(row + j) * N + col] = f2bf(v);
        else
          ((float*)out)[(row + j) * N + col] = v;
      }
    }
  }
}

// ---------- causal flash attention, QBLK=128, KVBLK=64, HDIM=64 ----------
// grid.x = 16 qtiles (heavy-first) * 64 bh; 8 waves, wave w owns Q rows w*16..+15.
// Swapped MFMA: S^T = mfma(K,Q) -> per-lane softmax state is scalar (q = lane&15).
// K/VT LDS tiles XOR-swizzled (physical chunk = logical ^ (row&7)) via pre-swizzled
// global source (linear gload_lds dest) + swizzled read. Double-buffered; raw
// s_barrier + counted vmcnt(2) so next tile's loads stay in flight across barriers.
__global__ __launch_bounds__(512) void k_attn(const unsigned short* __restrict__ qkv,
                                              const unsigned short* __restrict__ vt,
                                              unsigned short* __restrict__ aout) {
  __shared__ __align__(16) unsigned short Ks[2][64 * 64];
  __shared__ __align__(16) unsigned short VTs[2][64 * 64];
  __shared__ __align__(16) unsigned short Ps[8][16 * 72];
  const int tid = threadIdx.x, lane = tid & 63, wid = tid >> 6;
  const int r16 = lane & 15, khi = lane >> 4;
  const int qt = 15 - (int)(blockIdx.x >> 6), bh = blockIdx.x & 63;
  const int b = bh >> 4, h = bh & 15;
  const long qrow0 = (long)b * 2048 + qt * 128;

  // staging lane map: wave w covers tile rows 8w..8w+7; source col pre-swizzled
  const int srow = wid * 8 + (lane >> 3);
  const int lck = (lane & 7) ^ (srow & 7);
  const unsigned short* kbase =
      qkv + ((long)b * 2048 + srow) * 3072 + 1024 + h * 64 + lck * 8;
  const unsigned short* vbase = vt + ((long)bh * 64 + srow) * 2048 + lck * 8;

  // Q fragment straight to registers (read once; no LDS)
  const long qrow = qrow0 + wid * 16 + r16;
  const short8 qf0 = *(const short8*)&qkv[qrow * 3072 + h * 64 + khi * 8];
  const short8 qf1 = *(const short8*)&qkv[qrow * 3072 + h * 64 + 32 + khi * 8];

  // prologue: stage tile 0
  gload_lds16(kbase, &Ks[0][wid * 512]);
  gload_lds16(vbase, &VTs[0][wid * 512]);

  const int ktmax = 2 * qt + 1;
  const int ktw = (qt * 128 + wid * 16 + 15) >> 6;  // last tile this wave computes
  const int qg = qt * 128 + wid * 16 + r16;         // this lane's global q row
  float m_run = -1e30f, l_run = 0.f;
  f32x4 o[4] = {};

  for (int kt = 0; kt <= ktmax; ++kt) {
    const int cur = kt & 1;
    __builtin_amdgcn_s_barrier();  // all waves done reading buf[cur^1]
    if (kt < ktmax) {
      gload_lds16(kbase + (long)(kt + 1) * 64 * 3072, &Ks[cur ^ 1][wid * 512]);
      gload_lds16(vbase + (kt + 1) * 64, &VTs[cur ^ 1][wid * 512]);
      asm volatile("s_waitcnt vmcnt(2)" ::: "memory");  // tile kt landed; kt+1 in flight
    } else {
      asm volatile("s_waitcnt vmcnt(0)" ::: "memory");
    }
    __builtin_amdgcn_s_barrier();  // buf[cur] visible to all waves
    if (kt > ktw) continue;  // wave's rows below this tile; barriers stay matched

    // S^T = mfma(K, Q): D[k][q], lane holds q = r16, k = 16n + khi*4 + j
    f32x4 s[4] = {};
    __builtin_amdgcn_s_setprio(1);
#pragma unroll
    for (int kk = 0; kk < 2; ++kk) {
      const int pc = ((kk * 4 + khi) ^ (r16 & 7)) * 8;  // swizzled chunk
      const short8 qf = kk ? qf1 : qf0;
#pragma unroll
      for (int n = 0; n < 4; ++n) {
        short8 kf = *(const short8*)&Ks[cur][(n * 16 + r16) * 64 + pc];
        s[n] = __builtin_amdgcn_mfma_f32_16x16x32_bf16(kf, qf, s[n], 0, 0, 0);
      }
    }
    __builtin_amdgcn_s_setprio(0);

    // scale + causal mask (wave-uniform predicate)
    const bool need_mask = (kt * 64 + 63) > (qt * 128 + wid * 16);
    const int ktB = kt * 64;
#pragma unroll
    for (int n = 0; n < 4; ++n)
#pragma unroll
      for (int j = 0; j < 4; ++j) {
        float v = s[n][j] * 0.125f;
        if (need_mask && (ktB + n * 16 + khi * 4 + j) > qg) v = -1e30f;
        s[n][j] = v;
      }

    // online softmax: scalar state per lane (q = r16); reduce 16 in-lane + 2 shfl
    float pm = s[0][0];
#pragma unroll
    for (int n = 0; n < 4; ++n)
#pragma unroll
      for (int j = 0; j < 4; ++j) pm = fmaxf(pm, s[n][j]);
    pm = fmaxf(pm, __shfl_xor(pm, 16, 64));
    pm = fmaxf(pm, __shfl_xor(pm, 32, 64));
    const float mn = fmaxf(m_run, pm);
    const float alpha = __expf(m_run - mn);
    m_run = mn;
    float rs = 0.f;
#pragma unroll
    for (int n = 0; n < 4; ++n)
#pragma unroll
      for (int j = 0; j < 4; ++j) {
        float e = __expf(s[n][j] - mn);
        s[n][j] = e;
        rs += e;
      }
    rs += __shfl_xor(rs, 16, 64);
    rs += __shfl_xor(rs, 32, 64);
    l_run = l_run * alpha + rs;
#pragma unroll
    for (int n = 0; n < 4; ++n)
#pragma unroll
      for (int j = 0; j < 4; ++j) o[n][j] *= alpha;

    // P -> LDS (wave-local, packed b64 writes); P[q][k] row-major [16][72]
#pragma unroll
    for (int n = 0; n < 4; ++n) {
      s16x4 pw;
#pragma unroll
      for (int j = 0; j < 4; ++j) pw[j] = (short)f2bf(s[n][j]);
      *(s16x4*)&Ps[wid][r16 * 72 + n * 16 + khi * 4] = pw;
    }

    // O^T += mfma(VT, P): D[d][q], accumulator col q = r16 (aligned with S^T)
    __builtin_amdgcn_s_setprio(1);
#pragma unroll
    for (int kk = 0; kk < 2; ++kk) {
      const short8 pf = *(const short8*)&Ps[wid][r16 * 72 + kk * 32 + khi * 8];
      const int pc = ((kk * 4 + khi) ^ (r16 & 7)) * 8;
#pragma unroll
      for (int n = 0; n < 4; ++n) {
        short8 vf = *(const short8*)&VTs[cur][(n * 16 + r16) * 64 + pc];
        o[n] = __builtin_amdgcn_mfma_f32_16x16x32_bf16(vf, pf, o[n], 0, 0, 0);
      }
    }
    __builtin_amdgcn_s_setprio(0);
  }

  // epilogue: lane's row is qrow (fixed); cols h*64 + 16n + 4*khi + j
  const float inv = 1.f / l_run;
#pragma unroll
  for (int n = 0; n < 4; ++n) {
    s16x4 ow;
#pragma unroll
    for (int j = 0; j < 4; ++j) ow[j] = (short)f2bf(o[n][j] * inv);
    *(s16x4*)&aout[qrow * 1024 + h * 64 + n * 16 + khi * 4] = ow;
  }
}

extern "C" void kernel_launch(void* const* d_in, const int* in_sizes, int n_in,
                              void* d_out, int out_size, void* d_ws, size_t ws_size,
                              hipStream_t stream) {
  (void)in_sizes; (void)n_in; (void)out_size; (void)ws_size;
  const float* x = (const float*)d_in[0];
  const float* Wqkv = (const float*)d_in[1];
  const float* bqkv = (const float*)d_in[2];
  const float* Wout = (const float*)d_in[3];
  const float* bout = (const float*)d_in[4];
  char* ws = (char*)d_ws;
  // Buffer plan (peak 88 MB):
  //   xb    [8192][1024] bf16 @ 0        (16 MB)  -- dead after GEMM1; aout aliases it
  //   wqkvt [3072][1024] bf16 @ 16 MB    ( 6 MB)
  //   woutt [1024][1024] bf16 @ 22 MB    ( 2 MB)
  //   qkv   [8192][3072] bf16 @ 24 MB    (48 MB)
  //   vt    [4096][2048] bf16 @ 72 MB    (16 MB)
  unsigned short* xb    = (unsigned short*)(ws + 0);
  unsigned short* wqkvt = (unsigned short*)(ws + (16l << 20));
  unsigned short* woutt = (unsigned short*)(ws + (22l << 20));
  unsigned short* qkv   = (unsigned short*)(ws + (24l << 20));
  unsigned short* vt    = (unsigned short*)(ws + (72l << 20));
  unsigned short* aout  = xb;  // alias: xb dead after GEMM1

  k_convert<<<4096, 256, 0, stream>>>(x, xb);
  k_transpose_w<<<768, 256, 0, stream>>>(Wqkv, wqkvt, 1024, 3072);
  k_transpose_w<<<256, 256, 0, stream>>>(Wout, woutt, 1024, 1024);
  k_gemm<1><<<64 * 24, 256, 0, stream>>>(xb, wqkvt, bqkv, qkv, 8192, 3072, 1024);
  k_transpose_v<<<2048, 256, 0, stream>>>(qkv, vt);
  k_attn<<<16 * 64, 512, 0, stream>>>(qkv, vt, aout);
  k_gemm<0><<<64 * 8, 256, 0, stream>>>(aout, woutt, bout, d_out, 8192, 1024, 1024);
}

// Round 6
// 263.195 us; speedup vs baseline: 1.8280x; 1.0869x over previous
//
#include <hip/hip_runtime.h>

typedef __attribute__((ext_vector_type(8))) short short8;
typedef __attribute__((ext_vector_type(4))) short s16x4;
typedef __attribute__((ext_vector_type(4))) float f32x4;

#define AS1 __attribute__((address_space(1)))
#define AS3 __attribute__((address_space(3)))

__device__ __forceinline__ void gload_lds16(const void* g, void* l) {
  __builtin_amdgcn_global_load_lds((const AS1 void*)g, (AS3 void*)l, 16, 0, 0);
}

__device__ __forceinline__ unsigned short f2bf(float f) {
  unsigned int u = __float_as_uint(f);
  u += 0x7fffu + ((u >> 16) & 1u);
  return (unsigned short)(u >> 16);
}

// ---------------- x: fp32 -> bf16, 8 elems/thread ----------------
__global__ __launch_bounds__(256) void k_convert(const float* __restrict__ in,
                                                 unsigned short* __restrict__ out) {
  long i = (long)blockIdx.x * 256 + threadIdx.x;
  const float4* p = (const float4*)in + i * 2;
  float4 a = p[0], b = p[1];
  short8 o;
  o[0] = (short)f2bf(a.x); o[1] = (short)f2bf(a.y);
  o[2] = (short)f2bf(a.z); o[3] = (short)f2bf(a.w);
  o[4] = (short)f2bf(b.x); o[5] = (short)f2bf(b.y);
  o[6] = (short)f2bf(b.z); o[7] = (short)f2bf(b.w);
  ((short8*)out)[i] = o;
}

// ---------- W [K][N] fp32 -> WT [N][K] bf16 (64x64 tiles) ----------
__global__ __launch_bounds__(256) void k_transpose_w(const float* __restrict__ w,
                                                     unsigned short* __restrict__ wt,
                                                     int K, int N) {
  __shared__ float t[64][65];
  const int tilesN = N >> 6;
  const int tk = blockIdx.x / tilesN, tn = blockIdx.x % tilesN;
  const int c = threadIdx.x & 63, r0 = (threadIdx.x >> 6) * 16;
#pragma unroll
  for (int i = 0; i < 16; ++i)
    t[r0 + i][c] = w[(long)(tk * 64 + r0 + i) * N + tn * 64 + c];
  __syncthreads();
#pragma unroll
  for (int i = 0; i < 16; ++i)
    wt[(long)(tn * 64 + r0 + i) * K + tk * 64 + c] = f2bf(t[c][r0 + i]);
}

// ---------- V part of qkv -> VT [bh*64 + d][2048] bf16 ----------
__global__ __launch_bounds__(256) void k_transpose_v(const unsigned short* __restrict__ qkv,
                                                     unsigned short* __restrict__ vt) {
  __shared__ __align__(16) unsigned short t[64][72];
  const int tt = blockIdx.x & 31, bh = blockIdx.x >> 5;
  const int b = bh >> 4, h = bh & 15;
  const int r = threadIdx.x >> 2, c0 = (threadIdx.x & 3) * 16;
  const unsigned short* src = qkv + (long)(b * 2048 + tt * 64 + r) * 3072 + 2048 + h * 64 + c0;
  *(short8*)&t[r][c0] = *(const short8*)src;
  *(short8*)&t[r][c0 + 8] = *(const short8*)(src + 8);
  __syncthreads();
  short8 w0, w1;
#pragma unroll
  for (int i = 0; i < 8; ++i) w0[i] = (short)t[c0 + i][r];
#pragma unroll
  for (int i = 0; i < 8; ++i) w1[i] = (short)t[c0 + 8 + i][r];
  unsigned short* dst = vt + (long)(bh * 64 + r) * 2048 + tt * 64 + c0;
  *(short8*)dst = w0;
  *(short8*)(dst + 8) = w1;
}

// ---------- GEMM: C[M][N] = A[M][K] @ BT[N][K]^T + bias, 128x128 tile ----------
// Counted-vmcnt double-buffer (attn-validated structure) + T2 XOR swizzle
// (pre-swizzled global source, linear gload_lds dest, swizzled fragment read)
// + XCD-aware block swizzle (grid % 8 == 0 for all uses).
template <int OUT_BF16>
__global__ __launch_bounds__(256) void k_gemm(const unsigned short* __restrict__ A,
                                              const unsigned short* __restrict__ BT,
                                              const float* __restrict__ bias,
                                              void* __restrict__ out,
                                              int M, int N, int K) {
  __shared__ __align__(16) unsigned short As[2][128 * 64];
  __shared__ __align__(16) unsigned short Bs[2][128 * 64];
  const int tid = threadIdx.x, lane = tid & 63, wid = tid >> 6;
  const int r16 = lane & 15, khi = lane >> 4;
  const int wr = wid >> 1, wc = wid & 1;
  const int tilesN = N >> 7;
  const int cpx = gridDim.x >> 3;  // grid % 8 == 0
  const int bid = ((int)blockIdx.x & 7) * cpx + ((int)blockIdx.x >> 3);
  const int tm = bid / tilesN, tn = bid % tilesN;
  const long m0 = (long)tm * 128, n0 = (long)tn * 128;
  f32x4 acc[4][4] = {};
  // staging: thread t covers row srow=t>>3, physical chunk t&7; source col
  // pre-swizzled so physical chunk c holds logical chunk c ^ (row&7).
  const int srow = tid >> 3;
  const int scol = ((tid & 7) ^ (srow & 7)) * 8;
  const unsigned short* aSrc = A + (m0 + srow) * K + scol;
  const unsigned short* bSrc = BT + (n0 + srow) * K + scol;
  unsigned short* aDst = &As[0][0] + tid * 8;
  unsigned short* bDst = &Bs[0][0] + tid * 8;
  const int nk = K >> 6;

  // prologue: stage K-tile 0 -> buf0
#pragma unroll
  for (int call = 0; call < 4; ++call) {
    gload_lds16(aSrc + (long)call * 32 * K, aDst + call * 2048);
    gload_lds16(bSrc + (long)call * 32 * K, bDst + call * 2048);
  }

  int cur = 0;
  for (int ki = 0; ki < nk; ++ki) {
    __builtin_amdgcn_s_barrier();  // all waves done reading buf[cur^1]
    if (ki + 1 < nk) {
      const long k0 = (long)(ki + 1) * 64;
#pragma unroll
      for (int call = 0; call < 4; ++call) {
        gload_lds16(aSrc + (long)call * 32 * K + k0, aDst + (cur ^ 1) * 8192 + call * 2048);
        gload_lds16(bSrc + (long)call * 32 * K + k0, bDst + (cur ^ 1) * 8192 + call * 2048);
      }
      asm volatile("s_waitcnt vmcnt(8)" ::: "memory");  // tile ki landed; ki+1 in flight
    } else {
      asm volatile("s_waitcnt vmcnt(0)" ::: "memory");
    }
    __builtin_amdgcn_s_barrier();  // buf[cur] visible
    __builtin_amdgcn_s_setprio(1);
#pragma unroll
    for (int kk = 0; kk < 2; ++kk) {
      const int pc = ((kk * 4 + khi) ^ (r16 & 7)) * 8;  // swizzled chunk
      short8 af[4], bf[4];
#pragma unroll
      for (int m = 0; m < 4; ++m)
        af[m] = *(const short8*)&As[cur][(wr * 64 + m * 16 + r16) * 64 + pc];
#pragma unroll
      for (int n = 0; n < 4; ++n)
        bf[n] = *(const short8*)&Bs[cur][(wc * 64 + n * 16 + r16) * 64 + pc];
#pragma unroll
      for (int m = 0; m < 4; ++m)
#pragma unroll
        for (int n = 0; n < 4; ++n)
          acc[m][n] = __builtin_amdgcn_mfma_f32_16x16x32_bf16(af[m], bf[n], acc[m][n], 0, 0, 0);
    }
    __builtin_amdgcn_s_setprio(0);
    cur ^= 1;
  }
  // epilogue: C layout col=lane&15, row=(lane>>4)*4+reg
#pragma unroll
  for (int m = 0; m < 4; ++m) {
    long row = m0 + wr * 64 + m * 16 + khi * 4;
#pragma unroll
    for (int n = 0; n < 4; ++n) {
      int col = (int)n0 + wc * 64 + n * 16 + r16;
      float bv = bias[col];
#pragma unroll
      for (int j = 0; j < 4; ++j) {
        float v = acc[m][n][j] + bv;
        if (OUT_BF16)
          ((unsigned short*)out)[(row + j) * N + col] = f2bf(v);
        else
          ((float*)out)[(row + j) * N + col] = v;
      }
    }
  }
}

// ---------- causal flash attention, QBLK=128, KVBLK=64, HDIM=64 ----------
// grid.x = 16 qtiles (heavy-first) * 64 bh; 8 waves, wave w owns Q rows w*16..+15.
// Swapped MFMA: S^T = mfma(K,Q) -> per-lane softmax state is scalar (q = lane&15).
// K/VT LDS tiles XOR-swizzled (physical chunk = logical ^ (row&7)) via pre-swizzled
// global source (linear gload_lds dest) + swizzled read. Double-buffered; raw
// s_barrier + counted vmcnt(2) so next tile's loads stay in flight across barriers.
__global__ __launch_bounds__(512) void k_attn(const unsigned short* __restrict__ qkv,
                                              const unsigned short* __restrict__ vt,
                                              unsigned short* __restrict__ aout) {
  __shared__ __align__(16) unsigned short Ks[2][64 * 64];
  __shared__ __align__(16) unsigned short VTs[2][64 * 64];
  __shared__ __align__(16) unsigned short Ps[8][16 * 72];
  const int tid = threadIdx.x, lane = tid & 63, wid = tid >> 6;
  const int r16 = lane & 15, khi = lane >> 4;
  const int qt = 15 - (int)(blockIdx.x >> 6), bh = blockIdx.x & 63;
  const int b = bh >> 4, h = bh & 15;
  const long qrow0 = (long)b * 2048 + qt * 128;

  // staging lane map: wave w covers tile rows 8w..8w+7; source col pre-swizzled
  const int srow = wid * 8 + (lane >> 3);
  const int lck = (lane & 7) ^ (srow & 7);
  const unsigned short* kbase =
      qkv + ((long)b * 2048 + srow) * 3072 + 1024 + h * 64 + lck * 8;
  const unsigned short* vbase = vt + ((long)bh * 64 + srow) * 2048 + lck * 8;

  // Q fragment straight to registers (read once; no LDS)
  const long qrow = qrow0 + wid * 16 + r16;
  const short8 qf0 = *(const short8*)&qkv[qrow * 3072 + h * 64 + khi * 8];
  const short8 qf1 = *(const short8*)&qkv[qrow * 3072 + h * 64 + 32 + khi * 8];

  // prologue: stage tile 0
  gload_lds16(kbase, &Ks[0][wid * 512]);
  gload_lds16(vbase, &VTs[0][wid * 512]);

  const int ktmax = 2 * qt + 1;
  const int ktw = (qt * 128 + wid * 16 + 15) >> 6;  // last tile this wave computes
  const int qg = qt * 128 + wid * 16 + r16;         // this lane's global q row
  float m_run = -1e30f, l_run = 0.f;
  f32x4 o[4] = {};

  for (int kt = 0; kt <= ktmax; ++kt) {
    const int cur = kt & 1;
    __builtin_amdgcn_s_barrier();  // all waves done reading buf[cur^1]
    if (kt < ktmax) {
      gload_lds16(kbase + (long)(kt + 1) * 64 * 3072, &Ks[cur ^ 1][wid * 512]);
      gload_lds16(vbase + (kt + 1) * 64, &VTs[cur ^ 1][wid * 512]);
      asm volatile("s_waitcnt vmcnt(2)" ::: "memory");  // tile kt landed; kt+1 in flight
    } else {
      asm volatile("s_waitcnt vmcnt(0)" ::: "memory");
    }
    __builtin_amdgcn_s_barrier();  // buf[cur] visible to all waves
    if (kt > ktw) continue;  // wave's rows below this tile; barriers stay matched

    // S^T = mfma(K, Q): D[k][q], lane holds q = r16, k = 16n + khi*4 + j
    f32x4 s[4] = {};
    __builtin_amdgcn_s_setprio(1);
#pragma unroll
    for (int kk = 0; kk < 2; ++kk) {
      const int pc = ((kk * 4 + khi) ^ (r16 & 7)) * 8;  // swizzled chunk
      const short8 qf = kk ? qf1 : qf0;
#pragma unroll
      for (int n = 0; n < 4; ++n) {
        short8 kf = *(const short8*)&Ks[cur][(n * 16 + r16) * 64 + pc];
        s[n] = __builtin_amdgcn_mfma_f32_16x16x32_bf16(kf, qf, s[n], 0, 0, 0);
      }
    }
    __builtin_amdgcn_s_setprio(0);

    // scale + causal mask (wave-uniform predicate)
    const bool need_mask = (kt * 64 + 63) > (qt * 128 + wid * 16);
    const int ktB = kt * 64;
#pragma unroll
    for (int n = 0; n < 4; ++n)
#pragma unroll
      for (int j = 0; j < 4; ++j) {
        float v = s[n][j] * 0.125f;
        if (need_mask && (ktB + n * 16 + khi * 4 + j) > qg) v = -1e30f;
        s[n][j] = v;
      }

    // online softmax: scalar state per lane (q = r16); reduce 16 in-lane + 2 shfl
    float pm = s[0][0];
#pragma unroll
    for (int n = 0; n < 4; ++n)
#pragma unroll
      for (int j = 0; j < 4; ++j) pm = fmaxf(pm, s[n][j]);
    pm = fmaxf(pm, __shfl_xor(pm, 16, 64));
    pm = fmaxf(pm, __shfl_xor(pm, 32, 64));
    const float mn = fmaxf(m_run, pm);
    const float alpha = __expf(m_run - mn);
    m_run = mn;
    float rs = 0.f;
#pragma unroll
    for (int n = 0; n < 4; ++n)
#pragma unroll
      for (int j = 0; j < 4; ++j) {
        float e = __expf(s[n][j] - mn);
        s[n][j] = e;
        rs += e;
      }
    rs += __shfl_xor(rs, 16, 64);
    rs += __shfl_xor(rs, 32, 64);
    l_run = l_run * alpha + rs;
#pragma unroll
    for (int n = 0; n < 4; ++n)
#pragma unroll
      for (int j = 0; j < 4; ++j) o[n][j] *= alpha;

    // P -> LDS (wave-local, packed b64 writes); P[q][k] row-major [16][72]
#pragma unroll
    for (int n = 0; n < 4; ++n) {
      s16x4 pw;
#pragma unroll
      for (int j = 0; j < 4; ++j) pw[j] = (short)f2bf(s[n][j]);
      *(s16x4*)&Ps[wid][r16 * 72 + n * 16 + khi * 4] = pw;
    }

    // O^T += mfma(VT, P): D[d][q], accumulator col q = r16 (aligned with S^T)
    __builtin_amdgcn_s_setprio(1);
#pragma unroll
    for (int kk = 0; kk < 2; ++kk) {
      const short8 pf = *(const short8*)&Ps[wid][r16 * 72 + kk * 32 + khi * 8];
      const int pc = ((kk * 4 + khi) ^ (r16 & 7)) * 8;
#pragma unroll
      for (int n = 0; n < 4; ++n) {
        short8 vf = *(const short8*)&VTs[cur][(n * 16 + r16) * 64 + pc];
        o[n] = __builtin_amdgcn_mfma_f32_16x16x32_bf16(vf, pf, o[n], 0, 0, 0);
      }
    }
    __builtin_amdgcn_s_setprio(0);
  }

  // epilogue: lane's row is qrow (fixed); cols h*64 + 16n + 4*khi + j
  const float inv = 1.f / l_run;
#pragma unroll
  for (int n = 0; n < 4; ++n) {
    s16x4 ow;
#pragma unroll
    for (int j = 0; j < 4; ++j) ow[j] = (short)f2bf(o[n][j] * inv);
    *(s16x4*)&aout[qrow * 1024 + h * 64 + n * 16 + khi * 4] = ow;
  }
}

extern "C" void kernel_launch(void* const* d_in, const int* in_sizes, int n_in,
                              void* d_out, int out_size, void* d_ws, size_t ws_size,
                              hipStream_t stream) {
  (void)in_sizes; (void)n_in; (void)out_size; (void)ws_size;
  const float* x = (const float*)d_in[0];
  const float* Wqkv = (const float*)d_in[1];
  const float* bqkv = (const float*)d_in[2];
  const float* Wout = (const float*)d_in[3];
  const float* bout = (const float*)d_in[4];
  char* ws = (char*)d_ws;
  // Buffer plan (peak 88 MB):
  //   xb    [8192][1024] bf16 @ 0        (16 MB)  -- dead after GEMM1; aout aliases it
  //   wqkvt [3072][1024] bf16 @ 16 MB    ( 6 MB)
  //   woutt [1024][1024] bf16 @ 22 MB    ( 2 MB)
  //   qkv   [8192][3072] bf16 @ 24 MB    (48 MB)
  //   vt    [4096][2048] bf16 @ 72 MB    (16 MB)
  unsigned short* xb    = (unsigned short*)(ws + 0);
  unsigned short* wqkvt = (unsigned short*)(ws + (16l << 20));
  unsigned short* woutt = (unsigned short*)(ws + (22l << 20));
  unsigned short* qkv   = (unsigned short*)(ws + (24l << 20));
  unsigned short* vt    = (unsigned short*)(ws + (72l << 20));
  unsigned short* aout  = xb;  // alias: xb dead after GEMM1

  k_convert<<<4096, 256, 0, stream>>>(x, xb);
  k_transpose_w<<<768, 256, 0, stream>>>(Wqkv, wqkvt, 1024, 3072);
  k_transpose_w<<<256, 256, 0, stream>>>(Wout, woutt, 1024, 1024);
  k_gemm<1><<<64 * 24, 256, 0, stream>>>(xb, wqkvt, bqkv, qkv, 8192, 3072, 1024);
  k_transpose_v<<<2048, 256, 0, stream>>>(qkv, vt);
  k_attn<<<16 * 64, 512, 0, stream>>>(qkv, vt, aout);
  k_gemm<0><<<64 * 8, 256, 0, stream>>>(aout, woutt, bout, d_out, 8192, 1024, 1024);
}